// Round 11
// baseline (219.491 us; speedup 1.0000x reference)
//
#include <hip/hip_runtime.h>
#include <math.h>

#define NB 128
#define DHH 512
#define MM 4096
#define DD 128
#define EPSV 1e-8f

typedef float f32x4 __attribute__((ext_vector_type(4)));

// d_out float offsets
#define HO_OFF 0
#define CN_OFF 65536
#define K_OFF  67174400
#define R_OFF  67190784

// d_ws float offsets (all scratch; written before read every call)
#define SBUF_F 1024
#define RACC_F (SBUF_F + 524288)
#define LMAX_F (RACC_F + 1048576)
#define LSUM_F (LMAX_F + 8192)
#define GH_F   (LSUM_F + 8192)
#define BRAW_F (GH_F + 196608)
#define EB_F   (BRAW_F + 128)
#define VB_F   (EB_F + 16384)
#define GZ_F   (VB_F + 16384)

struct Seg { int jend; const float* W; const float* B; float* dst; int stride; int act; };

__device__ __forceinline__ float sigm(float x){ return 1.0f/(1.0f+expf(-x)); }

// Generic small-GEMM: out[n, j] = act( X[n,:K] . W[j,:K] + B[j] ), 8 j's per block.
template<int K>
__global__ __launch_bounds__(512) void proj8(const float* __restrict__ X, Seg s0, Seg s1, Seg s2)
{
    __shared__ float wlds[8][K];
    __shared__ float red[4][128][9];
    int t = threadIdx.x;
    int jbase = blockIdx.x * 8;
    for (int idx = t; idx < 8*K; idx += 512){
        int jj = idx / K, kk = idx - jj*K;
        int j = jbase + jj;
        const float* wrow = nullptr;
        if (j < s0.jend) wrow = s0.W + (size_t)j * K;
        else if (j < s1.jend) wrow = s1.W + (size_t)(j - s0.jend) * K;
        else if (j < s2.jend) wrow = s2.W + (size_t)(j - s1.jend) * K;
        wlds[jj][kk] = wrow ? wrow[kk] : 0.0f;
    }
    __syncthreads();
    {
        int n = t & 127, q = t >> 7;
        const int KQ = K/4;
        float acc[8];
        #pragma unroll
        for (int jj=0;jj<8;jj++) acc[jj]=0.0f;
        const float4* xrow4 = (const float4*)(X + (size_t)n*K + q*KQ);
        const float* wq = &wlds[0][0] + q*KQ;
        for (int k4=0; k4<KQ/4; ++k4){
            float4 xv = xrow4[k4];
            #pragma unroll
            for (int jj=0;jj<8;jj++){
                float4 wv = *(const float4*)(wq + jj*K + k4*4);
                acc[jj] = fmaf(xv.x, wv.x, fmaf(xv.y, wv.y, fmaf(xv.z, wv.z, fmaf(xv.w, wv.w, acc[jj]))));
            }
        }
        #pragma unroll
        for (int jj=0;jj<8;jj++) red[q][n][jj] = acc[jj];
    }
    __syncthreads();
    if (t < 128){
        #pragma unroll
        for (int jj=0;jj<8;jj++){
            int j = jbase + jj;
            const Seg* sg = nullptr; int loc = 0;
            if (j < s0.jend){ sg=&s0; loc=j; }
            else if (j < s1.jend){ sg=&s1; loc=j-s0.jend; }
            else if (j < s2.jend){ sg=&s2; loc=j-s1.jend; }
            if (sg){
                float v = red[0][t][jj]+red[1][t][jj]+red[2][t][jj]+red[3][t][jj] + sg->B[loc];
                if (sg->act==1) v = sigm(v);
                sg->dst[(size_t)t * sg->stride + loc] = v;
            }
        }
    }
}

// ---------------- device bodies (byte-identical math to R4) ----------------

__device__ void abTile(int n, int chunk,
                       const float* __restrict__ C, const float* __restrict__ kv,
                       const float* __restrict__ braw,
                       float* __restrict__ sbuf, float* __restrict__ racc,
                       float* __restrict__ lmaxb, float* __restrict__ lsumb)
{
    __shared__ float rlds[4][128];
    __shared__ float wred[2][4];
    int t = threadIdx.x;
    int mbase = chunk << 6;
    int tk = (n << 6) | chunk;
    int lane = t & 63, w = t >> 6;
    int s = t & 15, rowg = t >> 4;

    const float4* k4 = (const float4*)(kv + (size_t)n*DD);
    float4 ka = k4[s*2], kb = k4[s*2+1];
    float kq = ka.x*ka.x+ka.y*ka.y+ka.z*ka.z+ka.w*ka.w
             + kb.x*kb.x+kb.y*kb.y+kb.z*kb.z+kb.w*kb.w;
    #pragma unroll
    for (int off=1; off<16; off<<=1) kq += __shfl_xor(kq, off);
    float knorm = sqrtf(kq);
    float b = braw[n];
    float beta = 1.0f + fmaxf(b, 0.0f) + log1pf(expf(-fabsf(b)));

    const float4* C4 = (const float4*)C;
    float4 av[4], bw[4];
    float sval[4];
    #pragma unroll
    for (int it=0; it<4; ++it){
        int m = mbase + it*16 + rowg;
        size_t ridx = ((size_t)n*MM + m)*32 + s*2;
        float4 a = C4[ridx], b4 = C4[ridx+1];
        av[it] = a; bw[it] = b4;
        float dot = a.x*ka.x + a.y*ka.y + a.z*ka.z + a.w*ka.w
                  + b4.x*kb.x + b4.y*kb.y + b4.z*kb.z + b4.w*kb.w;
        float nr  = a.x*a.x + a.y*a.y + a.z*a.z + a.w*a.w
                  + b4.x*b4.x + b4.y*b4.y + b4.z*b4.z + b4.w*b4.w;
        #pragma unroll
        for (int off=1; off<16; off<<=1){
            dot += __shfl_xor(dot, off);
            nr  += __shfl_xor(nr, off);
        }
        float sv = beta * dot / fmaxf(sqrtf(nr)*knorm, EPSV);
        sval[it] = sv;
        if (s == 0) sbuf[(size_t)n*MM + m] = sv;
    }
    float lm = fmaxf(fmaxf(sval[0],sval[1]), fmaxf(sval[2],sval[3]));
    lm = fmaxf(lm, __shfl_xor(lm, 16));
    lm = fmaxf(lm, __shfl_xor(lm, 32));
    if (lane == 0) wred[0][w] = lm;
    __syncthreads();
    float lmax = fmaxf(fmaxf(wred[0][0], wred[0][1]), fmaxf(wred[0][2], wred[0][3]));

    float r8[8] = {0,0,0,0,0,0,0,0};
    float ps = 0.0f;
    #pragma unroll
    for (int it=0; it<4; ++it){
        float p = expf(sval[it] - lmax);
        ps += p;
        r8[0] = fmaf(p, av[it].x, r8[0]); r8[1] = fmaf(p, av[it].y, r8[1]);
        r8[2] = fmaf(p, av[it].z, r8[2]); r8[3] = fmaf(p, av[it].w, r8[3]);
        r8[4] = fmaf(p, bw[it].x, r8[4]); r8[5] = fmaf(p, bw[it].y, r8[5]);
        r8[6] = fmaf(p, bw[it].z, r8[6]); r8[7] = fmaf(p, bw[it].w, r8[7]);
    }
    ps += __shfl_xor(ps, 16); ps += __shfl_xor(ps, 32);
    #pragma unroll
    for (int j=0;j<8;j++){
        r8[j] += __shfl_xor(r8[j], 16);
        r8[j] += __shfl_xor(r8[j], 32);
    }
    if (lane < 16){
        #pragma unroll
        for (int j=0;j<8;j++) rlds[w][lane*8+j] = r8[j];
    }
    if (lane == 0) wred[1][w] = ps;
    __syncthreads();
    if (t < 128)
        racc[(size_t)tk*128 + t] = rlds[0][t]+rlds[1][t]+rlds[2][t]+rlds[3][t];
    if (t == 0){
        lmaxb[tk] = lmax;
        lsumb[tk] = wred[1][0]+wred[1][1]+wred[1][2]+wred[1][3];
    }
}

__device__ void midFn(int n,
                      const float* __restrict__ racc, const float* __restrict__ lmaxb,
                      const float* __restrict__ lsumb, const float* __restrict__ gh,
                      const float* __restrict__ hp,
                      const float* __restrict__ W_ih, const float* __restrict__ b_ih,
                      const float* __restrict__ We, const float* __restrict__ be,
                      const float* __restrict__ Wv, const float* __restrict__ bv,
                      float* __restrict__ r_out, float* __restrict__ ho,
                      float* __restrict__ gz, float* __restrict__ ebuf,
                      float* __restrict__ vbuf)
{
    __shared__ float alpha[64];
    __shared__ __align__(16) float rsh[128];
    __shared__ float gish[1536];
    __shared__ __align__(16) float hosh[512];
    __shared__ float zsh;
    int t = threadIdx.x;
    if (t < 64){
        float lm = lmaxb[n*64 + t];
        float gm = lm;
        #pragma unroll
        for (int off=1; off<64; off<<=1) gm = fmaxf(gm, __shfl_xor(gm, off));
        float a = expf(lm - gm);
        alpha[t] = a;
        float zc = a * lsumb[n*64 + t];
        #pragma unroll
        for (int off=1; off<64; off<<=1) zc += __shfl_xor(zc, off);
        if (t == 0){ zsh = zc; gz[n] = gm; gz[128+n] = 1.0f/zc; }
    }
    __syncthreads();
    float invZ = 1.0f / zsh;
    if (t < 128){
        const float* rb = racc + (size_t)n*64*128 + t;
        float acc = 0.0f;
        #pragma unroll 8
        for (int c=0; c<64; c++) acc = fmaf(alpha[c], rb[c*128], acc);
        float rv = acc * invZ;
        rsh[t] = rv;
        r_out[n*DD + t] = rv;
    }
    __syncthreads();
    {
        const float4* r4 = (const float4*)rsh;
        #pragma unroll
        for (int u=0; u<6; u++){
            int j = t + 256*u;
            const float4* wr = (const float4*)(W_ih + (size_t)j*DD);
            float acc = b_ih[j];
            #pragma unroll 8
            for (int kk=0; kk<32; kk++){
                float4 ww = wr[kk], rr = r4[kk];
                acc = fmaf(ww.x, rr.x, fmaf(ww.y, rr.y, fmaf(ww.z, rr.z, fmaf(ww.w, rr.w, acc))));
            }
            gish[j] = acc;
        }
    }
    __syncthreads();
    {
        const float* ghr = gh + (size_t)n*1536;
        #pragma unroll
        for (int u=0; u<2; u++){
            int j = t + 256*u;
            float rg = sigm(gish[j] + ghr[j]);
            float z  = sigm(gish[512+j] + ghr[512+j]);
            float ng = tanhf(gish[1024+j] + rg*ghr[1024+j]);
            float h  = hp[(size_t)n*DHH + j];
            float hv = (1.0f - z)*ng + z*h;
            hosh[j] = hv;
            ho[(size_t)n*DHH + j] = hv;
        }
    }
    __syncthreads();
    {
        const float* Wrow = (t < 128) ? (We + (size_t)t*DHH) : (Wv + (size_t)(t-128)*DHH);
        float acc = (t < 128) ? be[t] : bv[t-128];
        const float4* w4 = (const float4*)Wrow;
        const float4* h4 = (const float4*)hosh;
        #pragma unroll 8
        for (int kk=0; kk<128; kk++){
            float4 ww = w4[kk], hh = h4[kk];
            acc = fmaf(ww.x, hh.x, fmaf(ww.y, hh.y, fmaf(ww.z, hh.z, fmaf(ww.w, hh.w, acc))));
        }
        if (t < 128) ebuf[n*DD + t] = sigm(acc);
        else         vbuf[n*DD + (t-128)] = acc;
    }
}

__device__ void cTile(int n, int mbase,
                      const float* __restrict__ C, const float* __restrict__ sbuf,
                      const float* __restrict__ gz,
                      const float* __restrict__ e, const float* __restrict__ v,
                      float* __restrict__ Cn)
{
    __shared__ float wl[64];
    int t = threadIdx.x;
    if (t < 64){
        float gm = gz[n], iz = gz[128+n];
        wl[t] = expf(sbuf[(size_t)n*MM + mbase + t] - gm) * iz;
    }
    __syncthreads();
    int l = t & 31, q = t >> 5;
    f32x4 e4 = ((const f32x4*)(e + (size_t)n*DD))[l];
    f32x4 v4 = ((const f32x4*)(v + (size_t)n*DD))[l];
    const f32x4* C4 = (const f32x4*)C;
    f32x4* Cn4 = (f32x4*)Cn;
    #pragma unroll
    for (int it=0; it<8; ++it){
        int m = mbase + it*8 + q;
        float wm = wl[it*8 + q];
        size_t ridx = ((size_t)n*MM + m)*32 + l;
        f32x4 c = C4[ridx];
        f32x4 o;
        o.x = fmaf(wm, v4.x, c.x * (1.0f - wm*e4.x));
        o.y = fmaf(wm, v4.y, c.y * (1.0f - wm*e4.y));
        o.z = fmaf(wm, v4.z, c.z * (1.0f - wm*e4.z));
        o.w = fmaf(wm, v4.w, c.w * (1.0f - wm*e4.w));
        __builtin_nontemporal_store(o, &Cn4[ridx]);
    }
}

// ---------------- kernels ----------------

// AB over h0, ascending
__global__ __launch_bounds__(256) void kAB0(const float* C, const float* kv, const float* braw,
                                            float* sbuf, float* racc, float* lmaxb, float* lsumb)
{
    int n = blockIdx.x >> 6, chunk = blockIdx.x & 63;
    abTile(n, chunk, C, kv, braw, sbuf, racc, lmaxb, lsumb);
}

// mid(h0) [blocks 0..63] + AB(h1) ascending [blocks 64..4159]
__global__ __launch_bounds__(256) void kMix1(const float* C, const float* kv, const float* braw,
                                             float* sbuf, float* racc, float* lmaxb, float* lsumb,
                                             const float* gh, const float* hp,
                                             const float* W_ih, const float* b_ih,
                                             const float* We, const float* be,
                                             const float* Wv, const float* bv,
                                             float* r_out, float* ho,
                                             float* gz, float* ebuf, float* vbuf)
{
    if (blockIdx.x < 64){
        midFn(blockIdx.x, racc, lmaxb, lsumb, gh, hp, W_ih, b_ih, We, be, Wv, bv,
              r_out, ho, gz, ebuf, vbuf);
    } else {
        int bid = blockIdx.x - 64;
        int n = 64 + (bid >> 6), chunk = bid & 63;
        abTile(n, chunk, C, kv, braw, sbuf, racc, lmaxb, lsumb);
    }
}

// mid(h1) [blocks 0..63] + C(h0) descending [blocks 64..4159]
__global__ __launch_bounds__(256) void kMix2(const float* C, const float* sbuf,
                                             const float* racc, const float* lmaxb, const float* lsumb,
                                             const float* gh, const float* hp,
                                             const float* W_ih, const float* b_ih,
                                             const float* We, const float* be,
                                             const float* Wv, const float* bv,
                                             float* r_out, float* ho,
                                             float* gz, float* ebuf, float* vbuf,
                                             float* Cn)
{
    if (blockIdx.x < 64){
        midFn(64 + blockIdx.x, racc, lmaxb, lsumb, gh, hp, W_ih, b_ih, We, be, Wv, bv,
              r_out, ho, gz, ebuf, vbuf);
    } else {
        int bid = 4095 - (int)(blockIdx.x - 64);   // descending over h0
        int n = bid >> 6, mbase = (bid & 63) << 6;
        cTile(n, mbase, C, sbuf, gz, ebuf, vbuf, Cn);
    }
}

// C(h1) descending
__global__ __launch_bounds__(256) void kC1(const float* C, const float* sbuf, const float* gz,
                                           const float* ebuf, const float* vbuf, float* Cn)
{
    int bid = 4095 - (int)blockIdx.x;              // descending over h1
    int n = 64 + (bid >> 6), mbase = (bid & 63) << 6;
    cTile(n, mbase, C, sbuf, gz, ebuf, vbuf, Cn);
}

extern "C" void kernel_launch(void* const* d_in, const int* in_sizes, int n_in,
                              void* d_out, int out_size, void* d_ws, size_t ws_size,
                              hipStream_t stream) {
    const float* hp   = (const float*)d_in[0];
    const float* C    = (const float*)d_in[1];
    const float* Wk   = (const float*)d_in[2];
    const float* bk   = (const float*)d_in[3];
    const float* Wb   = (const float*)d_in[4];
    const float* bb   = (const float*)d_in[5];
    const float* We   = (const float*)d_in[6];
    const float* be   = (const float*)d_in[7];
    const float* Wv   = (const float*)d_in[8];
    const float* bv   = (const float*)d_in[9];
    const float* W_ih = (const float*)d_in[10];
    const float* b_ih = (const float*)d_in[11];
    const float* W_hh = (const float*)d_in[12];
    const float* b_hh = (const float*)d_in[13];

    float* out   = (float*)d_out;
    float* ho    = out + HO_OFF;
    float* Cn    = out + CN_OFF;
    float* k_out = out + K_OFF;
    float* r_out = out + R_OFF;

    float* wsf   = (float*)d_ws;
    float* sbuf  = wsf + SBUF_F;
    float* racc  = wsf + RACC_F;
    float* lmaxb = wsf + LMAX_F;
    float* lsumb = wsf + LSUM_F;
    float* gh    = wsf + GH_F;
    float* braw  = wsf + BRAW_F;
    float* ebuf  = wsf + EB_F;
    float* vbuf  = wsf + VB_F;
    float* gz    = wsf + GZ_F;

    // 1) k, gh, beta_pre (from h_o_prev, K=512)
    {
        Seg s0 = {128, Wk, bk, k_out, 128, 0};
        Seg s1 = {1664, W_hh, b_hh, gh, 1536, 0};
        Seg s2 = {1665, Wb, bb, braw, 1, 0};
        proj8<512><<<209, 512, 0, stream>>>(hp, s0, s1, s2);
    }
    // 2) AB(h0) ascending
    kAB0<<<4096, 256, 0, stream>>>(C, k_out, braw, sbuf, racc, lmaxb, lsumb);
    // 3) mid(h0) hidden inside AB(h1)
    kMix1<<<4160, 256, 0, stream>>>(C, k_out, braw, sbuf, racc, lmaxb, lsumb,
                                    gh, hp, W_ih, b_ih, We, be, Wv, bv,
                                    r_out, ho, gz, ebuf, vbuf);
    // 4) mid(h1) hidden inside C(h0) (descending; h0 hot in L3)
    kMix2<<<4160, 256, 0, stream>>>(C, sbuf, racc, lmaxb, lsumb,
                                    gh, hp, W_ih, b_ih, We, be, Wv, bv,
                                    r_out, ho, gz, ebuf, vbuf, Cn);
    // 5) C(h1) descending (h1 hot in L3 from step 3)
    kC1<<<4096, 256, 0, stream>>>(C, sbuf, gz, ebuf, vbuf, Cn);
}

// Round 12
// 199.296 us; speedup vs baseline: 1.1013x; 1.1013x over previous
//
#include <hip/hip_runtime.h>
#include <math.h>

#define NB 128
#define DHH 512
#define MM 4096
#define DD 128
#define EPSV 1e-8f

typedef float f32x4 __attribute__((ext_vector_type(4)));

// d_out float offsets
#define HO_OFF 0
#define CN_OFF 65536
#define K_OFF  67174400
#define R_OFF  67190784

// d_ws float offsets (all scratch; written before read every call)
#define SBUF_F 1024
#define RACC_F (SBUF_F + 524288)
#define LMAX_F (RACC_F + 1048576)
#define LSUM_F (LMAX_F + 8192)
#define GH_F   (LSUM_F + 8192)
#define BRAW_F (GH_F + 196608)
#define EB_F   (BRAW_F + 128)
#define VB_F   (EB_F + 16384)
#define GZ_F   (VB_F + 16384)

struct Seg { int jend; const float* W; const float* B; float* dst; int stride; int act; };

__device__ __forceinline__ float sigm(float x){ return 1.0f/(1.0f+expf(-x)); }

// Generic small-GEMM: out[n, j] = act( X[n,:K] . W[j,:K] + B[j] ), 8 j's per block.
template<int K>
__global__ __launch_bounds__(512) void proj8(const float* __restrict__ X, Seg s0, Seg s1, Seg s2)
{
    __shared__ float wlds[8][K];
    __shared__ float red[4][128][9];
    int t = threadIdx.x;
    int jbase = blockIdx.x * 8;
    for (int idx = t; idx < 8*K; idx += 512){
        int jj = idx / K, kk = idx - jj*K;
        int j = jbase + jj;
        const float* wrow = nullptr;
        if (j < s0.jend) wrow = s0.W + (size_t)j * K;
        else if (j < s1.jend) wrow = s1.W + (size_t)(j - s0.jend) * K;
        else if (j < s2.jend) wrow = s2.W + (size_t)(j - s1.jend) * K;
        wlds[jj][kk] = wrow ? wrow[kk] : 0.0f;
    }
    __syncthreads();
    {
        int n = t & 127, q = t >> 7;
        const int KQ = K/4;
        float acc[8];
        #pragma unroll
        for (int jj=0;jj<8;jj++) acc[jj]=0.0f;
        const float4* xrow4 = (const float4*)(X + (size_t)n*K + q*KQ);
        const float* wq = &wlds[0][0] + q*KQ;
        for (int k4=0; k4<KQ/4; ++k4){
            float4 xv = xrow4[k4];
            #pragma unroll
            for (int jj=0;jj<8;jj++){
                float4 wv = *(const float4*)(wq + jj*K + k4*4);
                acc[jj] = fmaf(xv.x, wv.x, fmaf(xv.y, wv.y, fmaf(xv.z, wv.z, fmaf(xv.w, wv.w, acc[jj]))));
            }
        }
        #pragma unroll
        for (int jj=0;jj<8;jj++) red[q][n][jj] = acc[jj];
    }
    __syncthreads();
    if (t < 128){
        #pragma unroll
        for (int jj=0;jj<8;jj++){
            int j = jbase + jj;
            const Seg* sg = nullptr; int loc = 0;
            if (j < s0.jend){ sg=&s0; loc=j; }
            else if (j < s1.jend){ sg=&s1; loc=j-s0.jend; }
            else if (j < s2.jend){ sg=&s2; loc=j-s1.jend; }
            if (sg){
                float v = red[0][t][jj]+red[1][t][jj]+red[2][t][jj]+red[3][t][jj] + sg->B[loc];
                if (sg->act==1) v = sigm(v);
                sg->dst[(size_t)t * sg->stride + loc] = v;
            }
        }
    }
}

// Fused pass A+B: each block processes TWO adjacent 64-m chunks of the same n
// (amortizes k-load / knorm / beta). Chunk math identical to R4 (bit-exact).
__global__ __launch_bounds__(256) void passAB(const float* __restrict__ C, const float* __restrict__ kv,
                                              const float* __restrict__ braw,
                                              float* __restrict__ sbuf, float* __restrict__ racc,
                                              float* __restrict__ lmaxb, float* __restrict__ lsumb)
{
    __shared__ float rlds[4][128];
    __shared__ float wred[2][4];
    int t = threadIdx.x;
    int n = blockIdx.x >> 5;
    int chunk0 = (blockIdx.x & 31) << 1;
    int lane = t & 63, w = t >> 6;
    int s = t & 15, rowg = t >> 4;

    const float4* k4 = (const float4*)(kv + (size_t)n*DD);
    float4 ka = k4[s*2], kb = k4[s*2+1];
    float kq = ka.x*ka.x+ka.y*ka.y+ka.z*ka.z+ka.w*ka.w
             + kb.x*kb.x+kb.y*kb.y+kb.z*kb.z+kb.w*kb.w;
    #pragma unroll
    for (int off=1; off<16; off<<=1) kq += __shfl_xor(kq, off);
    float knorm = sqrtf(kq);
    float b = braw[n];
    float beta = 1.0f + fmaxf(b, 0.0f) + log1pf(expf(-fabsf(b)));

    const float4* C4 = (const float4*)C;

    #pragma unroll 1
    for (int cc = 0; cc < 2; ++cc){
        int chunk = chunk0 + cc;
        int mbase = chunk << 6;
        int tk = (n << 6) | chunk;

        float4 av[4], bw[4];
        float sval[4];
        #pragma unroll
        for (int it=0; it<4; ++it){
            int m = mbase + it*16 + rowg;
            size_t ridx = ((size_t)n*MM + m)*32 + s*2;
            float4 a = C4[ridx], b4 = C4[ridx+1];
            av[it] = a; bw[it] = b4;
            float dot = a.x*ka.x + a.y*ka.y + a.z*ka.z + a.w*ka.w
                      + b4.x*kb.x + b4.y*kb.y + b4.z*kb.z + b4.w*kb.w;
            float nr  = a.x*a.x + a.y*a.y + a.z*a.z + a.w*a.w
                      + b4.x*b4.x + b4.y*b4.y + b4.z*b4.z + b4.w*b4.w;
            #pragma unroll
            for (int off=1; off<16; off<<=1){
                dot += __shfl_xor(dot, off);
                nr  += __shfl_xor(nr, off);
            }
            float sv = beta * dot / fmaxf(sqrtf(nr)*knorm, EPSV);
            sval[it] = sv;
            if (s == 0) sbuf[(size_t)n*MM + m] = sv;
        }
        float lm = fmaxf(fmaxf(sval[0],sval[1]), fmaxf(sval[2],sval[3]));
        lm = fmaxf(lm, __shfl_xor(lm, 16));
        lm = fmaxf(lm, __shfl_xor(lm, 32));
        if (lane == 0) wred[0][w] = lm;
        __syncthreads();
        float lmax = fmaxf(fmaxf(wred[0][0], wred[0][1]), fmaxf(wred[0][2], wred[0][3]));

        float r8[8] = {0,0,0,0,0,0,0,0};
        float ps = 0.0f;
        #pragma unroll
        for (int it=0; it<4; ++it){
            float p = expf(sval[it] - lmax);
            ps += p;
            r8[0] = fmaf(p, av[it].x, r8[0]); r8[1] = fmaf(p, av[it].y, r8[1]);
            r8[2] = fmaf(p, av[it].z, r8[2]); r8[3] = fmaf(p, av[it].w, r8[3]);
            r8[4] = fmaf(p, bw[it].x, r8[4]); r8[5] = fmaf(p, bw[it].y, r8[5]);
            r8[6] = fmaf(p, bw[it].z, r8[6]); r8[7] = fmaf(p, bw[it].w, r8[7]);
        }
        ps += __shfl_xor(ps, 16); ps += __shfl_xor(ps, 32);
        #pragma unroll
        for (int j=0;j<8;j++){
            r8[j] += __shfl_xor(r8[j], 16);
            r8[j] += __shfl_xor(r8[j], 32);
        }
        if (lane < 16){
            #pragma unroll
            for (int j=0;j<8;j++) rlds[w][lane*8+j] = r8[j];
        }
        if (lane == 0) wred[1][w] = ps;
        __syncthreads();
        if (t < 128)
            racc[(size_t)tk*128 + t] = rlds[0][t]+rlds[1][t]+rlds[2][t]+rlds[3][t];
        if (t == 0){
            lmaxb[tk] = lmax;
            lsumb[tk] = wred[1][0]+wred[1][1]+wred[1][2]+wred[1][3];
        }
        if (cc == 0) __syncthreads();   // LDS reuse hazard between chunks
    }
}

// Fused per-n: combine -> r, gz; gi = r@W_ih^T; GRU gates -> h_o; e,v = h_o@{We,Wv}^T
__global__ __launch_bounds__(256) void mid(const float* __restrict__ racc, const float* __restrict__ lmaxb,
                                           const float* __restrict__ lsumb, const float* __restrict__ gh,
                                           const float* __restrict__ hp,
                                           const float* __restrict__ W_ih, const float* __restrict__ b_ih,
                                           const float* __restrict__ We, const float* __restrict__ be,
                                           const float* __restrict__ Wv, const float* __restrict__ bv,
                                           float* __restrict__ r_out, float* __restrict__ ho,
                                           float* __restrict__ gz, float* __restrict__ ebuf,
                                           float* __restrict__ vbuf)
{
    __shared__ float alpha[64];
    __shared__ __align__(16) float rsh[128];
    __shared__ float gish[1536];
    __shared__ __align__(16) float hosh[512];
    __shared__ float zsh;
    int n = blockIdx.x, t = threadIdx.x;
    if (t < 64){
        float lm = lmaxb[n*64 + t];
        float gm = lm;
        #pragma unroll
        for (int off=1; off<64; off<<=1) gm = fmaxf(gm, __shfl_xor(gm, off));
        float a = expf(lm - gm);
        alpha[t] = a;
        float zc = a * lsumb[n*64 + t];
        #pragma unroll
        for (int off=1; off<64; off<<=1) zc += __shfl_xor(zc, off);
        if (t == 0){ zsh = zc; gz[n] = gm; gz[128+n] = 1.0f/zc; }
    }
    __syncthreads();
    float invZ = 1.0f / zsh;
    if (t < 128){
        const float* rb = racc + (size_t)n*64*128 + t;
        float acc = 0.0f;
        #pragma unroll 8
        for (int c=0; c<64; c++) acc = fmaf(alpha[c], rb[c*128], acc);
        float rv = acc * invZ;
        rsh[t] = rv;
        r_out[n*DD + t] = rv;
    }
    __syncthreads();
    {
        const float4* r4 = (const float4*)rsh;
        #pragma unroll
        for (int u=0; u<6; u++){
            int j = t + 256*u;
            const float4* wr = (const float4*)(W_ih + (size_t)j*DD);
            float acc = b_ih[j];
            #pragma unroll 8
            for (int kk=0; kk<32; kk++){
                float4 ww = wr[kk], rr = r4[kk];
                acc = fmaf(ww.x, rr.x, fmaf(ww.y, rr.y, fmaf(ww.z, rr.z, fmaf(ww.w, rr.w, acc))));
            }
            gish[j] = acc;
        }
    }
    __syncthreads();
    {
        const float* ghr = gh + (size_t)n*1536;
        #pragma unroll
        for (int u=0; u<2; u++){
            int j = t + 256*u;
            float rg = sigm(gish[j] + ghr[j]);
            float z  = sigm(gish[512+j] + ghr[512+j]);
            float ng = tanhf(gish[1024+j] + rg*ghr[1024+j]);
            float h  = hp[(size_t)n*DHH + j];
            float hv = (1.0f - z)*ng + z*h;
            hosh[j] = hv;
            ho[(size_t)n*DHH + j] = hv;
        }
    }
    __syncthreads();
    {
        const float* Wrow = (t < 128) ? (We + (size_t)t*DHH) : (Wv + (size_t)(t-128)*DHH);
        float acc = (t < 128) ? be[t] : bv[t-128];
        const float4* w4 = (const float4*)Wrow;
        const float4* h4 = (const float4*)hosh;
        #pragma unroll 8
        for (int kk=0; kk<128; kk++){
            float4 ww = w4[kk], hh = h4[kk];
            acc = fmaf(ww.x, hh.x, fmaf(ww.y, hh.y, fmaf(ww.z, hh.z, fmaf(ww.w, hh.w, acc))));
        }
        if (t < 128) ebuf[n*DD + t] = sigm(acc);
        else         vbuf[n*DD + (t-128)] = acc;
    }
}

// Pass C: one block = one 128-m-row tile (2 R4 chunks), REVERSED order + nt stores.
__global__ __launch_bounds__(256) void passC(const float* __restrict__ C, const float* __restrict__ sbuf,
                                             const float* __restrict__ gz,
                                             const float* __restrict__ e, const float* __restrict__ v,
                                             float* __restrict__ Cn)
{
    __shared__ float wl[128];
    int t = threadIdx.x;
    int bid = (int)(gridDim.x - 1 - blockIdx.x);
    int n = bid >> 5, mbase = (bid & 31) << 7;
    if (t < 128){
        float gm = gz[n], iz = gz[128+n];
        wl[t] = expf(sbuf[(size_t)n*MM + mbase + t] - gm) * iz;
    }
    __syncthreads();
    int l = t & 31, q = t >> 5;
    f32x4 e4 = ((const f32x4*)(e + (size_t)n*DD))[l];
    f32x4 v4 = ((const f32x4*)(v + (size_t)n*DD))[l];
    const f32x4* C4 = (const f32x4*)C;
    f32x4* Cn4 = (f32x4*)Cn;
    #pragma unroll
    for (int it=0; it<16; ++it){
        int m = mbase + it*8 + q;
        float wm = wl[it*8 + q];
        size_t ridx = ((size_t)n*MM + m)*32 + l;
        f32x4 c = C4[ridx];
        f32x4 o;
        o.x = fmaf(wm, v4.x, c.x * (1.0f - wm*e4.x));
        o.y = fmaf(wm, v4.y, c.y * (1.0f - wm*e4.y));
        o.z = fmaf(wm, v4.z, c.z * (1.0f - wm*e4.z));
        o.w = fmaf(wm, v4.w, c.w * (1.0f - wm*e4.w));
        __builtin_nontemporal_store(o, &Cn4[ridx]);
    }
}

extern "C" void kernel_launch(void* const* d_in, const int* in_sizes, int n_in,
                              void* d_out, int out_size, void* d_ws, size_t ws_size,
                              hipStream_t stream) {
    const float* hp   = (const float*)d_in[0];
    const float* C    = (const float*)d_in[1];
    const float* Wk   = (const float*)d_in[2];
    const float* bk   = (const float*)d_in[3];
    const float* Wb   = (const float*)d_in[4];
    const float* bb   = (const float*)d_in[5];
    const float* We   = (const float*)d_in[6];
    const float* be   = (const float*)d_in[7];
    const float* Wv   = (const float*)d_in[8];
    const float* bv   = (const float*)d_in[9];
    const float* W_ih = (const float*)d_in[10];
    const float* b_ih = (const float*)d_in[11];
    const float* W_hh = (const float*)d_in[12];
    const float* b_hh = (const float*)d_in[13];

    float* out   = (float*)d_out;
    float* ho    = out + HO_OFF;
    float* Cn    = out + CN_OFF;
    float* k_out = out + K_OFF;
    float* r_out = out + R_OFF;

    float* wsf   = (float*)d_ws;
    float* sbuf  = wsf + SBUF_F;
    float* racc  = wsf + RACC_F;
    float* lmaxb = wsf + LMAX_F;
    float* lsumb = wsf + LSUM_F;
    float* gh    = wsf + GH_F;
    float* braw  = wsf + BRAW_F;
    float* ebuf  = wsf + EB_F;
    float* vbuf  = wsf + VB_F;
    float* gz    = wsf + GZ_F;

    // 1) k, gh, beta_pre (from h_o_prev, K=512)
    {
        Seg s0 = {128, Wk, bk, k_out, 128, 0};
        Seg s1 = {1664, W_hh, b_hh, gh, 1536, 0};
        Seg s2 = {1665, Wb, bb, braw, 1, 0};
        proj8<512><<<209, 512, 0, stream>>>(hp, s0, s1, s2);
    }
    // 2) fused scores + online-softmax partials (2 chunks/block)
    passAB<<<4096, 256, 0, stream>>>(C, k_out, braw, sbuf, racc, lmaxb, lsumb);
    // 3) combine + gi + gates + e,v (one kernel, per-n blocks)
    mid<<<128, 256, 0, stream>>>(racc, lmaxb, lsumb, gh, hp, W_ih, b_ih,
                                 We, be, Wv, bv, r_out, ho, gz, ebuf, vbuf);
    // 4) C_new = C*(1 - w*e) + w*v (128-row tiles, reverse order + nt stores)
    passC<<<4096, 256, 0, stream>>>(C, sbuf, gz, ebuf, vbuf, Cn);
}